// Round 5
// baseline (535.855 us; speedup 1.0000x reference)
//
#include <hip/hip_runtime.h>
#include <hip/hip_bf16.h>

#define Bn 128
#define Hd 512
#define Nn 1024

typedef __attribute__((ext_vector_type(8))) short short8;
typedef __attribute__((ext_vector_type(4))) float f32x4;

#define GLOAD_LDS16(gptr, lptr)                                                     \
    __builtin_amdgcn_global_load_lds(                                               \
        (const __attribute__((address_space(1))) void*)(gptr),                      \
        (__attribute__((address_space(3))) void*)(lptr), 16, 0, 0)

// packed RNE f32x2 -> bf16x2 (compiler emits v_cvt_pk_bf16_f32)
__device__ __forceinline__ unsigned pack_bf2(float a, float b) {
    __hip_bfloat162 h = __float22bfloat162_rn(float2{a, b});
    unsigned u;
    __builtin_memcpy(&u, &h, 4);
    return u;
}

__device__ __forceinline__ float wave_sum(float v) {
    v += __shfl_xor(v, 32);
    v += __shfl_xor(v, 16);
    v += __shfl_xor(v, 8);
    v += __shfl_xor(v, 4);
    v += __shfl_xor(v, 2);
    v += __shfl_xor(v, 1);
    return v;
}

__device__ __forceinline__ float tanh_fast(float x) {
    float e = __expf(2.0f * x);
    return 1.0f - 2.0f * __builtin_amdgcn_rcpf(e + 1.0f);
}

// ---------------------------------------------------------------------------
// K0: fused preprocessing.
//   blocks [0,128):    Wb[h][k] = bf16(attn_W[h][k]), k in [0,512)
//   blocks [128,16512): mc_term[b,h] = sum_k attn_W[h,512+k]*mc[b,k]  (fp32)
// ---------------------------------------------------------------------------
__global__ void pre_kernel(const float* __restrict__ attn_W,
                           const float* __restrict__ mc,
                           unsigned short* __restrict__ Wb,
                           float* __restrict__ mc_term) {
    if (blockIdx.x < 128) {
        int idx = (blockIdx.x * 256 + threadIdx.x) * 8;
        int h = idx >> 9;
        int k = idx & 511;
        const float* p = attn_W + (size_t)h * 1024 + k;
        float4 v0 = *(const float4*)p;
        float4 v1 = *(const float4*)(p + 4);
        unsigned u[4] = {pack_bf2(v0.x, v0.y), pack_bf2(v0.z, v0.w),
                         pack_bf2(v1.x, v1.y), pack_bf2(v1.z, v1.w)};
        *(uint4*)(Wb + idx) = *(uint4*)u;
        return;
    }
    int wg = ((blockIdx.x - 128) * 256 + threadIdx.x) >> 6;
    int lane = threadIdx.x & 63;
    int b = wg >> 9;
    int h = wg & 511;
    const float* m = mc + b * Hd + lane * 8;
    const float* w = attn_W + (size_t)h * 1024 + 512 + lane * 8;
    float4 m0 = *(const float4*)m, m1 = *(const float4*)(m + 4);
    float4 w0 = *(const float4*)w, w1 = *(const float4*)(w + 4);
    float acc = m0.x * w0.x + m0.y * w0.y + m0.z * w0.z + m0.w * w0.w +
                m1.x * w1.x + m1.y * w1.y + m1.z * w1.z + m1.w * w1.w;
    acc = wave_sum(acc);
    if (lane == 0) mc_term[b * Hd + h] = acc;
}

// ---------------------------------------------------------------------------
// K2: scores_part[mh][b][n] -- MFMA GEMM, fused in-kernel B transpose.
// OCCUPANCY REWORK: 8 waves x (64m x 64n) tiles, 512 threads.
//   acc = 4x4 f32x4 = 64 VGPR (was 128) -> target <=128 total,
//   __launch_bounds__(512,4) => 16 waves/CU (4/SIMD), 2x the latency hiding.
// Same BM=256 x BN=128 x BK=64 tiles, same staging traffic, bit-identical
// accumulation order (k0 asc, kk asc) -> absmax must stay 0.0078125.
// ---------------------------------------------------------------------------
__global__ __launch_bounds__(512, 4)
void attn_score_kernel(const float* __restrict__ sn,
                       const unsigned short* __restrict__ Wb,
                       const float* __restrict__ attn_v,
                       const float* __restrict__ mc_term,
                       float* __restrict__ scores_part) {
    __shared__ __align__(16) unsigned short A_lds[256 * 64];  // [m][k] 32KB
    __shared__ __align__(16) unsigned short B_lds[128 * 64];  // [n][k] 16KB
    __shared__ float av_s[256];
    __shared__ float mct_s[256];
    __shared__ float ssum[128];

    const int bid = blockIdx.x;
    const int b = bid >> 4;
    const int mh = (bid >> 3) & 1;        // m-half: rows [mh*256, mh*256+256)
    const int n0 = (bid & 7) << 7;        // 128-wide n tile
    const int tid = threadIdx.x;
    const int lane = tid & 63;
    const int wid = tid >> 6;             // 0..7
    const int wr = wid >> 1;              // m-tile: rows [wr*64, wr*64+64)
    const int wc = wid & 1;               // n-tile: cols [wc*64, wc*64+64)
    const int quad = lane >> 4;
    const int l15 = lane & 15;

    if (tid < 256) {
        av_s[tid] = attn_v[mh * 256 + tid];
        mct_s[tid] = mc_term[b * Hd + mh * 256 + tid];
    }
    if (tid < 128) ssum[tid] = 0.f;

    f32x4 acc[4][4];
#pragma unroll
    for (int i = 0; i < 4; ++i)
#pragma unroll
        for (int j = 0; j < 4; ++j) {
            f32x4 z = {0.f, 0.f, 0.f, 0.f};
            acc[i][j] = z;
        }

    const int r8 = lane >> 3;                  // A-staging row within 8-group
    const int csw = ((lane & 7) ^ r8) * 16;    // A swizzled chunk byte offset
    const char* Wg = (const char*)Wb + (size_t)(mh * 256) * 1024;
    const int key = l15 & 7;

    // B staging map: thread -> k-chunk wid (8 rows), n-columns lane, lane+64
    const int bswz = ((wid ^ (lane & 7)) * 16);   // chunk ^ (row&7), loop-inv
    const float* snB = sn + (size_t)b * Hd * Nn + (size_t)(8 * wid) * Nn + n0 + lane;

    for (int k0 = 0; k0 < 512; k0 += 64) {
        // stage A: wave stages 32 m-rows, 4 global_load_lds x 1KB
#pragma unroll
        for (int i = 0; i < 4; ++i) {
            const int row = wid * 32 + i * 8;
            GLOAD_LDS16(Wg + (size_t)(row + r8) * 1024 + k0 * 2 + csw,
                        (char*)A_lds + row * 128);
        }
        // stage B: per (n, wid): 8 k-rows (coalesced dwords) -> 1 b128 write
        {
            const float* pk = snB + (size_t)k0 * Nn;
#pragma unroll
            for (int j = 0; j < 2; ++j) {
                const int n = lane + 64 * j;
                const float* p = pk + 64 * j;
                float v0 = p[0 * Nn], v1 = p[1 * Nn], v2 = p[2 * Nn], v3 = p[3 * Nn];
                float v4 = p[4 * Nn], v5 = p[5 * Nn], v6 = p[6 * Nn], v7 = p[7 * Nn];
                unsigned kp[4] = {pack_bf2(v0, v1), pack_bf2(v2, v3),
                                  pack_bf2(v4, v5), pack_bf2(v6, v7)};
                *(uint4*)((char*)B_lds + n * 128 + bswz) = *(uint4*)kp;
            }
        }
        __syncthreads();
        __builtin_amdgcn_s_setprio(1);
#pragma unroll
        for (int kk = 0; kk < 2; ++kk) {
            const int cb = quad + kk * 4;      // k-chunk: k_local = cb*8..+8
            short8 bfr[4], afr[4];
#pragma unroll
            for (int nt = 0; nt < 4; ++nt) {
                const int nl = wc * 64 + nt * 16 + l15;
                bfr[nt] = *(const short8*)((const char*)B_lds + nl * 128 + ((cb ^ key) * 16));
            }
#pragma unroll
            for (int mt = 0; mt < 4; ++mt) {
                const int m = wr * 64 + mt * 16 + l15;
                afr[mt] = *(const short8*)((const char*)A_lds + m * 128 + ((cb ^ key) * 16));
            }
#pragma unroll
            for (int mt = 0; mt < 4; ++mt)
#pragma unroll
                for (int nt = 0; nt < 4; ++nt)
                    acc[mt][nt] = __builtin_amdgcn_mfma_f32_16x16x32_bf16(afr[mt], bfr[nt], acc[mt][nt], 0, 0, 0);
        }
        __builtin_amdgcn_s_setprio(0);
        __syncthreads();
    }

    // epilogue: tanh + attn_v dot over wave's 64 h, reduce, store part
    float s[4] = {0.f, 0.f, 0.f, 0.f};
#pragma unroll
    for (int mt = 0; mt < 4; ++mt) {
        int hb = wr * 64 + mt * 16 + quad * 4;
#pragma unroll
        for (int r = 0; r < 4; ++r) {
            float av = av_s[hb + r];
            float mcv = mct_s[hb + r];
#pragma unroll
            for (int nt = 0; nt < 4; ++nt)
                s[nt] += av * tanh_fast(acc[mt][nt][r] + mcv);
        }
    }
#pragma unroll
    for (int nt = 0; nt < 4; ++nt) {
        float v = s[nt];
        v += __shfl_xor(v, 16);
        v += __shfl_xor(v, 32);
        if (lane < 16) atomicAdd(&ssum[wc * 64 + nt * 16 + l15], v);
    }
    __syncthreads();
    if (tid < 128)
        scores_part[((size_t)mh * Bn + b) * Nn + n0 + tid] = ssum[tid];
}

// ---------------------------------------------------------------------------
// K3+K4 fused: softmax stats recomputed per block (8 KB redundant read),
// then context[b,h] = sum_n attns[b,n] * sn[b][h][n]   (fp32, no atomics)
// block = (b, 64 h). thread: h = h0 + t>>2, n-phase q = t&3.
// ---------------------------------------------------------------------------
__global__ void softmax_context_kernel(const float* __restrict__ sn,
                                       const float* __restrict__ scores_part,
                                       float* __restrict__ context) {
    int b = blockIdx.x >> 3;
    int h0 = (blockIdx.x & 7) << 6;
    int t = threadIdx.x;
    int lane = t & 63, wid = t >> 6;
    __shared__ float red[4];
    __shared__ float a_s[1024];

    const float* s0 = scores_part + (size_t)b * Nn;
    const float* s1 = scores_part + ((size_t)Bn + b) * Nn;
    float v[4];
#pragma unroll
    for (int i = 0; i < 4; ++i) {
        int idx = t + i * 256;
        v[i] = s0[idx] + s1[idx];
    }
    float m = fmaxf(fmaxf(v[0], v[1]), fmaxf(v[2], v[3]));
#pragma unroll
    for (int off = 32; off >= 1; off >>= 1) m = fmaxf(m, __shfl_xor(m, off));
    if (lane == 0) red[wid] = m;
    __syncthreads();
    m = fmaxf(fmaxf(red[0], red[1]), fmaxf(red[2], red[3]));
    __syncthreads();
    float s = 0.f;
#pragma unroll
    for (int i = 0; i < 4; ++i) {
        v[i] = __expf(v[i] - m);
        s += v[i];
    }
    s = wave_sum(s);
    if (lane == 0) red[wid] = s;
    __syncthreads();
    s = red[0] + red[1] + red[2] + red[3];
    float inv = __builtin_amdgcn_rcpf(s);
#pragma unroll
    for (int i = 0; i < 4; ++i) a_s[t + i * 256] = v[i] * inv;
    __syncthreads();

    int h = h0 + (t >> 2), q = t & 3;
    const float* row = sn + ((size_t)b * Hd + h) * Nn;
    float acc = 0.f;
#pragma unroll 8
    for (int j = 0; j < 64; ++j) {
        int n = q * 4 + j * 16;
        float4 f = *(const float4*)&row[n];
        float4 a = *(const float4*)&a_s[n];
        acc += f.x * a.x + f.y * a.y + f.z * a.z + f.w * a.w;
    }
    acc += __shfl_xor(acc, 1);
    acc += __shfl_xor(acc, 2);
    if (q == 0) context[b * Hd + h] = acc;
}

// ---------------------------------------------------------------------------
// K5: out1[b,h] = relu( dot([mc|context], fc1_W[h,:]) + fc1_b[h] )   (fp32)
// ---------------------------------------------------------------------------
__global__ void fc1_kernel(const float* __restrict__ mc,
                           const float* __restrict__ ctx,
                           const float* __restrict__ fc1_W,
                           const float* __restrict__ fc1_b,
                           float* __restrict__ out1) {
    int wg = (blockIdx.x * blockDim.x + threadIdx.x) >> 6;
    int lane = threadIdx.x & 63;
    int b = wg >> 9, h = wg & 511;
    const float* wr = fc1_W + (size_t)h * 1024;
    float acc = 0.f;
    {
        float4 w0 = *(const float4*)(wr + lane * 8);
        float4 w1 = *(const float4*)(wr + lane * 8 + 4);
        float4 x0 = *(const float4*)(mc + b * Hd + lane * 8);
        float4 x1 = *(const float4*)(mc + b * Hd + lane * 8 + 4);
        acc += w0.x * x0.x + w0.y * x0.y + w0.z * x0.z + w0.w * x0.w;
        acc += w1.x * x1.x + w1.y * x1.y + w1.z * x1.z + w1.w * x1.w;
    }
    {
        float4 w0 = *(const float4*)(wr + 512 + lane * 8);
        float4 w1 = *(const float4*)(wr + 512 + lane * 8 + 4);
        float4 x0 = *(const float4*)(ctx + b * Hd + lane * 8);
        float4 x1 = *(const float4*)(ctx + b * Hd + lane * 8 + 4);
        acc += w0.x * x0.x + w0.y * x0.y + w0.z * x0.z + w0.w * x0.w;
        acc += w1.x * x1.x + w1.y * x1.y + w1.z * x1.z + w1.w * x1.w;
    }
    acc = wave_sum(acc);
    if (lane == 0) out1[b * Hd + h] = fmaxf(acc + fc1_b[h], 0.f);
}

// ---------------------------------------------------------------------------
// K6: out2[b,h] = relu( dot(out1, fc2_W[h,:]) + fc2_b[h] )   (fp32)
// ---------------------------------------------------------------------------
__global__ void fc2_kernel(const float* __restrict__ out1,
                           const float* __restrict__ fc2_W,
                           const float* __restrict__ fc2_b,
                           float* __restrict__ out2) {
    int wg = (blockIdx.x * blockDim.x + threadIdx.x) >> 6;
    int lane = threadIdx.x & 63;
    int b = wg >> 9, h = wg & 511;
    const float* wr = fc2_W + (size_t)h * 512 + lane * 8;
    float4 w0 = *(const float4*)wr;
    float4 w1 = *(const float4*)(wr + 4);
    float4 x0 = *(const float4*)(out1 + b * Hd + lane * 8);
    float4 x1 = *(const float4*)(out1 + b * Hd + lane * 8 + 4);
    float acc = w0.x * x0.x + w0.y * x0.y + w0.z * x0.z + w0.w * x0.w +
                w1.x * x1.x + w1.y * x1.y + w1.z * x1.z + w1.w * x1.w;
    acc = wave_sum(acc);
    if (lane == 0) out2[b * Hd + h] = fmaxf(acc + fc2_b[h], 0.f);
}

// ---------------------------------------------------------------------------
// K7: probs[b,n] = sum_h ptr_v[h] * tanh( sn[b][h][n] + out2[b,h] )  (fp32)
// block = (b, 256-n chunk); wave w covers h in [w*128, w*128+128).
// ---------------------------------------------------------------------------
__global__ void final_kernel(const float* __restrict__ sn,
                             const float* __restrict__ ptr_v,
                             const float* __restrict__ out2,
                             float* __restrict__ probs) {
    int b = blockIdx.x >> 2;
    int n0 = (blockIdx.x & 3) << 8;
    int t = threadIdx.x;
    int w = t >> 6, l = t & 63;
    __shared__ float pv_s[512], o2_s[512];
    __shared__ float fsum[4][256];
    pv_s[t] = ptr_v[t];
    pv_s[t + 256] = ptr_v[t + 256];
    o2_s[t] = out2[b * Hd + t];
    o2_s[t + 256] = out2[b * Hd + t + 256];
    __syncthreads();
    const float* col = sn + (size_t)b * Hd * Nn + n0 + l * 4;
    float a0 = 0.f, a1 = 0.f, a2 = 0.f, a3 = 0.f;
#pragma unroll 4
    for (int j = 0; j < 128; ++j) {
        int h = w * 128 + j;
        float4 f = *(const float4*)&col[(size_t)h * Nn];
        float p = pv_s[h], o = o2_s[h];
        a0 += p * tanh_fast(f.x + o);
        a1 += p * tanh_fast(f.y + o);
        a2 += p * tanh_fast(f.z + o);
        a3 += p * tanh_fast(f.w + o);
    }
    fsum[w][l * 4 + 0] = a0;
    fsum[w][l * 4 + 1] = a1;
    fsum[w][l * 4 + 2] = a2;
    fsum[w][l * 4 + 3] = a3;
    __syncthreads();
    float r = fsum[0][t & 255] + fsum[1][t & 255] + fsum[2][t & 255] + fsum[3][t & 255];
    probs[b * Nn + n0 + (t & 255)] = r;
}

// ---------------------------------------------------------------------------
extern "C" void kernel_launch(void* const* d_in, const int* in_sizes, int n_in,
                              void* d_out, int out_size, void* d_ws, size_t ws_size,
                              hipStream_t stream) {
    const float* mc  = (const float*)d_in[0];
    const float* sn  = (const float*)d_in[1];
    const float* aW  = (const float*)d_in[2];
    const float* av  = (const float*)d_in[3];
    const float* pv  = (const float*)d_in[4];
    const float* f1W = (const float*)d_in[5];
    const float* f1b = (const float*)d_in[6];
    const float* f2W = (const float*)d_in[7];
    const float* f2b = (const float*)d_in[8];

    unsigned short* Wb = (unsigned short*)d_ws;             // 512 KB
    float* fws         = (float*)(Wb + 512 * 512);
    float* mc_term     = fws;                               // 256 KB
    float* scores_part = mc_term + Bn * Hd;                 // 2 x 512 KB
    float* context     = scores_part + 2 * Bn * Nn;         // 256 KB
    float* out1        = context + Bn * Hd;
    float* out2        = out1 + Bn * Hd;
    float* probs       = (float*)d_out;

    pre_kernel<<<dim3(16512), dim3(256), 0, stream>>>(aW, mc, Wb, mc_term);
    attn_score_kernel<<<dim3(2048), dim3(512), 0, stream>>>(sn, Wb, av, mc_term, scores_part);
    softmax_context_kernel<<<dim3(1024), dim3(256), 0, stream>>>(sn, scores_part, context);
    fc1_kernel<<<dim3(16384), dim3(256), 0, stream>>>(mc, context, f1W, f1b, out1);
    fc2_kernel<<<dim3(16384), dim3(256), 0, stream>>>(out1, f2W, f2b, out2);
    final_kernel<<<dim3(512), dim3(256), 0, stream>>>(sn, pv, out2, probs);
}